// Round 12
// baseline (45.541 us; speedup 1.0000x reference)
//
#include <hip/hip_runtime.h>
#include <hip/hip_bf16.h>
#include <math.h>

#define BB 4
#define CCH 128     // channels
#define HH 64
#define WW 256
#define RR 8
#define KWIN 17
#define TW 32       // output w-tile per block
#define TWH 48      // TW + 2R (halo)
#define NTHREADS 256
#define PIT 136     // fBt/gT pitch (shorts)
#define FAP 48      // fA pitch (shorts)
#define PTP 48      // Pt pitch (shorts)
#define PT_HI 5440  // short offset of Pt rows 16..31 inside uA
#define MROWS 144

typedef __attribute__((ext_vector_type(8))) short short8;
typedef __attribute__((ext_vector_type(4))) short short4v;
typedef __attribute__((ext_vector_type(4))) float f32x4;

__device__ __forceinline__ short f2bf(float x) {
    union { __hip_bfloat16 b; short s; } u;
    u.b = __float2bfloat16(x);
    return u.s;
}

// ---- prep: M' bf16 [144][128] = [Wq^T Wk ; (Wk^T bq)^T ; zeros] into d_ws ----
__global__ __launch_bounds__(128)
void prep_kernel(const float* __restrict__ Wq, const float* __restrict__ bq,
                 const float* __restrict__ Wk, short* __restrict__ Mp)
{
    const int r = blockIdx.x;      // 0..143
    const int c = threadIdx.x;     // 0..127
    float acc = 0.f;
    if (r < CCH) {
        #pragma unroll 4
        for (int j = 0; j < CCH; ++j)
            acc = fmaf(Wq[j * CCH + r], Wk[j * CCH + c], acc);
    } else if (r == CCH) {
        #pragma unroll 4
        for (int o = 0; o < CCH; ++o)
            acc = fmaf(bq[o], Wk[o * CCH + c], acc);
    }
    Mp[r * CCH + c] = f2bf(acc);
}

// St embedded in gT region: St row r lives inside the 16-row gT block (r>>4)
// that only wave (r>>4) reads -> write-after-own-read, no cross-wave race.
#define ST_IDX(r) (((r) >> 4) * 1088 + ((r) & 15) * 36)   // float index into uB

__global__ __launch_bounds__(NTHREADS, 4)
void attn1d_fused(const float* __restrict__ feature,
                  const float* __restrict__ position,
                  const short* __restrict__ Mp,
                  float* __restrict__ out)
{
    // uA: fBt [48][136] (stage->C); Pt overlays fBt rows 0..7 / 40..47 (C-dead)
    // uB: gT [48][136] (B->C); St embedded per-16-row block (C->softmax)
    __shared__ __align__(16) char uA[TWH * PIT * 2];     // 13056
    __shared__ __align__(16) char uB[TWH * PIT * 2];     // 13056
    __shared__ __align__(16) short fA[CCH][FAP];         // 12288  f [c][wl]
    __shared__ float ubias[TWH];                         //   192
                                                         // total 38592 -> 4 blocks/CU
    short (*fBt)[PIT] = (short(*)[PIT])uA;
    short (*gT)[PIT]  = (short(*)[PIT])uB;
    float* Stp        = (float*)uB;
    short* uAs        = (short*)uA;

    const int t    = threadIdx.x;
    const int wid  = t >> 6;
    const int lane = t & 63;
    const int lrow = lane & 15;
    const int lgrp = lane >> 4;

    // XCD-chunked bijective swizzle (2048 % 8 == 0)
    int blk = blockIdx.x;
    blk = (blk & 7) * 256 + (blk >> 3);
    const int wt = blk & 7;
    const int bh = blk >> 3;
    const int h  = bh & (HH - 1);
    const int b  = bh >> 6;
    const int w0 = wt * TW - RR;
    const int base = ((b * CCH) * HH + h) * WW;

    // ---------------- Phase A: stage f (branch-free single load burst) -------
    // idx = i*256+t; cp = idx/12 (c-pair), wq = idx%12. Loads clamped in-bounds
    // and issued unconditionally (one vmcnt window); OOB lanes zero via select.
    int cA[3], wqA[3];
    short4v sA0[3], sA1[3];             // kept for deferred fA write (Phase B)
    bool inbA[3];
    #pragma unroll
    for (int i = 0; i < 3; ++i) {
        const int idx = i * NTHREADS + t;        // 0..767
        const int cp  = idx / 12;
        const int wq  = idx - cp * 12;
        const int c0  = cp * 2;
        const int w   = w0 + wq * 4;             // quad fully in or out
        const bool inb = (w >= 0) && (w < WW);
        const int wc  = inb ? w : RR;            // safe clamped address
        const int off = base + c0 * (HH * WW) + wc;
        const float4 fa0 = *(const float4*)(feature + off);
        const float4 pa0 = *(const float4*)(position + off);
        const float4 fa1 = *(const float4*)(feature + off + HH * WW);
        const float4 pa1 = *(const float4*)(position + off + HH * WW);
        short4v s0, s1;
        s0[0] = f2bf(inb ? fa0.x + pa0.x : 0.f);
        s0[1] = f2bf(inb ? fa0.y + pa0.y : 0.f);
        s0[2] = f2bf(inb ? fa0.z + pa0.z : 0.f);
        s0[3] = f2bf(inb ? fa0.w + pa0.w : 0.f);
        s1[0] = f2bf(inb ? fa1.x + pa1.x : 0.f);
        s1[1] = f2bf(inb ? fa1.y + pa1.y : 0.f);
        s1[2] = f2bf(inb ? fa1.z + pa1.z : 0.f);
        s1[3] = f2bf(inb ? fa1.w + pa1.w : 0.f);
        cA[i] = c0; wqA[i] = wq; sA0[i] = s0; sA1[i] = s1; inbA[i] = inb;
        #pragma unroll
        for (int j = 0; j < 4; ++j) {
            const unsigned uv = (unsigned)(unsigned short)s0[j]
                              | ((unsigned)(unsigned short)s1[j] << 16);
            *(unsigned*)&fBt[wq * 4 + j][c0] = uv;   // packed c-pair, low conflicts
        }
    }

    // ---- M-fragments from ws (bf16, direct 16B loads; L2-hot broadcast) ------
    const int mrow = wid * 32;
    short8 Mf[2][4];            // [mf][kk] rows mrow..mrow+31
    #pragma unroll
    for (int mf = 0; mf < 2; ++mf)
        #pragma unroll
        for (int kk = 0; kk < 4; ++kk)
            Mf[mf][kk] = *(const short8*)(Mp + (mrow + mf * 16 + lrow) * CCH
                                             + kk * 32 + lgrp * 8);
    short8 Mf2[4];              // wave 3 only: u-row 128
    if (wid == 3) {
        #pragma unroll
        for (int kk = 0; kk < 4; ++kk)
            Mf2[kk] = *(const short8*)(Mp + (CCH + lrow) * CCH + kk * 32 + lgrp * 8);
    }
    __syncthreads();

    // ---------------- Phase B: g = M f via MFMA (all 4 waves, 32 rows each) ---
    {
        f32x4 acc[2][3];
        #pragma unroll
        for (int mf = 0; mf < 2; ++mf)
            #pragma unroll
            for (int nf = 0; nf < 3; ++nf)
                acc[mf][nf] = (f32x4){0.f, 0.f, 0.f, 0.f};
        f32x4 acc2[3];
        #pragma unroll
        for (int nf = 0; nf < 3; ++nf) acc2[nf] = (f32x4){0.f, 0.f, 0.f, 0.f};

        __builtin_amdgcn_s_setprio(1);
        #pragma unroll
        for (int kk = 0; kk < 4; ++kk) {
            short8 bfr[3];
            #pragma unroll
            for (int nf = 0; nf < 3; ++nf)
                bfr[nf] = *(const short8*)&fBt[nf * 16 + lrow][kk * 32 + lgrp * 8];
            #pragma unroll
            for (int mf = 0; mf < 2; ++mf)
                #pragma unroll
                for (int nf = 0; nf < 3; ++nf)
                    acc[mf][nf] = __builtin_amdgcn_mfma_f32_16x16x32_bf16(
                        Mf[mf][kk], bfr[nf], acc[mf][nf], 0, 0, 0);
            if (wid == 3) {
                #pragma unroll
                for (int nf = 0; nf < 3; ++nf)
                    acc2[nf] = __builtin_amdgcn_mfma_f32_16x16x32_bf16(
                        Mf2[kk], bfr[nf], acc2[nf], 0, 0, 0);
            }
        }
        __builtin_amdgcn_s_setprio(0);

        // deferred fA writes (read only in Phase D, after barrier 4): hide here
        #pragma unroll
        for (int i = 0; i < 3; ++i) {
            *(short4v*)&fA[cA[i]    ][wqA[i] * 4] = sA0[i];
            *(short4v*)&fA[cA[i] + 1][wqA[i] * 4] = sA1[i];
        }

        // writeback g^T (bf16): rows wl = nf*16+lrow, cols mrow+mf*16+lgrp*4+reg
        #pragma unroll
        for (int mf = 0; mf < 2; ++mf)
            #pragma unroll
            for (int nf = 0; nf < 3; ++nf) {
                short4v s;
                #pragma unroll
                for (int reg = 0; reg < 4; ++reg)
                    s[reg] = f2bf(acc[mf][nf][reg]);
                *(short4v*)&gT[nf * 16 + lrow][mrow + mf * 16 + lgrp * 4] = s;
            }
        if (wid == 3 && lgrp == 0) {
            const float isc = 0.08838834764831845f;
            #pragma unroll
            for (int nf = 0; nf < 3; ++nf)
                ubias[nf * 16 + lrow] = acc2[nf][0] * isc;
        }
    }
    __syncthreads();

    // ---------------- Phase C: S^T = (f^T g) / sqrt(C) via MFMA ---------------
    if (wid < 3) {
        const int nf = wid;          // wl' block 0..2
        f32x4 s0 = {0.f,0.f,0.f,0.f}, s1 = {0.f,0.f,0.f,0.f};
        __builtin_amdgcn_s_setprio(1);
        #pragma unroll
        for (int kk = 0; kk < 4; ++kk) {
            const short8 a0 = *(const short8*)&fBt[RR + lrow     ][kk * 32 + lgrp * 8];
            const short8 a1 = *(const short8*)&fBt[RR + 16 + lrow][kk * 32 + lgrp * 8];
            const short8 bb = *(const short8*)&gT[nf * 16 + lrow][kk * 32 + lgrp * 8];
            s0 = __builtin_amdgcn_mfma_f32_16x16x32_bf16(a0, bb, s0, 0, 0, 0);
            s1 = __builtin_amdgcn_mfma_f32_16x16x32_bf16(a1, bb, s1, 0, 0, 0);
        }
        __builtin_amdgcn_s_setprio(0);
        const float isc = 0.08838834764831845f;   // 1/sqrt(128)
        const int sb = ST_IDX(nf * 16 + lrow);    // write inside own gT block
        *(f32x4*)&Stp[sb + lgrp * 4]      = s0 * isc;
        *(f32x4*)&Stp[sb + 16 + lgrp * 4] = s1 * isc;
    } else {
        // wave 3: zero-fill Pt (overlay in fBt rows 0..7 / 40..47, C-dead)
        const short8 z = {0,0,0,0,0,0,0,0};
        #pragma unroll
        for (int i = 0; i < 2; ++i) {
            const int q8 = i * 64 + lane;         // 96 short8 per half
            if (q8 < 96) {
                *(short8*)(uAs + q8 * 8) = z;            // Pt rows 0..15
                *(short8*)(uAs + PT_HI + q8 * 8) = z;    // Pt rows 16..31
            }
        }
    }
    __syncthreads();

    // ---------------- softmax over 17 taps (8 threads/row, all 256) ----------
    {
        const int w = t >> 3, g = t & 7;
        const int nt = (g == 0) ? 3 : 2;          // taps j = g, g+8, (g==0 -> 16)
        const int prow = (w < 16) ? (w * PTP) : (PT_HI + (w - 16) * PTP);
        float sv[3];
        float mx = -3.0e38f;
        #pragma unroll
        for (int i = 0; i < 3; ++i) {
            if (i < nt) {
                const int j = (i == 2) ? 16 : (g + i * 8);
                const int r = w + j;
                sv[i] = Stp[ST_IDX(r) + w] + ubias[r];
                mx = fmaxf(mx, sv[i]);
            }
        }
        mx = fmaxf(mx, __shfl_xor(mx, 1, 8));
        mx = fmaxf(mx, __shfl_xor(mx, 2, 8));
        mx = fmaxf(mx, __shfl_xor(mx, 4, 8));
        float sum = 0.f;
        #pragma unroll
        for (int i = 0; i < 3; ++i)
            if (i < nt) { sv[i] = __expf(sv[i] - mx); sum += sv[i]; }
        sum += __shfl_xor(sum, 1, 8);
        sum += __shfl_xor(sum, 2, 8);
        sum += __shfl_xor(sum, 4, 8);
        const float inv = 1.f / sum;
        #pragma unroll
        for (int i = 0; i < 3; ++i)
            if (i < nt) {
                const int j = (i == 2) ? 16 : (g + i * 8);
                uAs[prow + w + j] = f2bf(sv[i] * inv);
            }
    }
    __syncthreads();

    // ---------------- Phase D: out = f . P^T via MFMA -------------------------
    // kk=1 & lgrp>=2 -> k-cols 48..63: both operands substituted zero.
    {
        const int cb = wid * 32;
        const short8 z = {0,0,0,0,0,0,0,0};
        f32x4 d00 = {0.f,0.f,0.f,0.f}, d01 = d00, d10 = d00, d11 = d00;
        #pragma unroll
        for (int kk = 0; kk < 2; ++kk) {
            const int koff = kk * 32 + lgrp * 8;
            const bool live = (koff < TWH);
            short8 a0 = z, a1 = z, b0 = z, b1 = z;
            if (live) {
                a0 = *(const short8*)&fA[cb + lrow     ][koff];
                a1 = *(const short8*)&fA[cb + 16 + lrow][koff];
                b0 = *(const short8*)(uAs + lrow * PTP + koff);           // Pt 0..15
                b1 = *(const short8*)(uAs + PT_HI + lrow * PTP + koff);   // Pt 16..31
            }
            d00 = __builtin_amdgcn_mfma_f32_16x16x32_bf16(a0, b0, d00, 0, 0, 0);
            d01 = __builtin_amdgcn_mfma_f32_16x16x32_bf16(a0, b1, d01, 0, 0, 0);
            d10 = __builtin_amdgcn_mfma_f32_16x16x32_bf16(a1, b0, d10, 0, 0, 0);
            d11 = __builtin_amdgcn_mfma_f32_16x16x32_bf16(a1, b1, d11, 0, 0, 0);
        }
        const int wbase = wt * TW;
        #pragma unroll
        for (int reg = 0; reg < 4; ++reg) {
            const int c0 = cb + lgrp * 4 + reg;
            out[base + c0 * (HH * WW)        + wbase + lrow]      = d00[reg];
            out[base + c0 * (HH * WW)        + wbase + 16 + lrow] = d01[reg];
            out[base + (c0 + 16) * (HH * WW) + wbase + lrow]      = d10[reg];
            out[base + (c0 + 16) * (HH * WW) + wbase + 16 + lrow] = d11[reg];
        }
    }
}

extern "C" void kernel_launch(void* const* d_in, const int* in_sizes, int n_in,
                              void* d_out, int out_size, void* d_ws, size_t ws_size,
                              hipStream_t stream) {
    const float* feature  = (const float*)d_in[0];
    const float* position = (const float*)d_in[1];
    const float* Wq = (const float*)d_in[2];
    const float* bq = (const float*)d_in[3];
    const float* Wk = (const float*)d_in[4];
    const float* bk = (const float*)d_in[5];   // only row-const softmax terms
    (void)bk;
    float* out = (float*)d_out;
    short* Mp  = (short*)d_ws;                 // 144x128 bf16 = 36864 B

    prep_kernel<<<MROWS, 128, 0, stream>>>(Wq, bq, Wk, Mp);
    const dim3 grid(BB * HH * (WW / TW));      // 2048 blocks, 4/CU -> 2 exact rounds
    attn1d_fused<<<grid, NTHREADS, 0, stream>>>(feature, position, Mp, out);
}

// Round 13
// 35.832 us; speedup vs baseline: 1.2710x; 1.2710x over previous
//
#include <hip/hip_runtime.h>
#include <hip/hip_bf16.h>
#include <math.h>

#define BB 4
#define CCH 128     // channels
#define HH 64
#define WW 256
#define RR 8
#define KWIN 17
#define TW 32       // output w-tile per block
#define TWH 48      // TW + 2R (halo)
#define NTHREADS 256
#define PIT 136     // fBt/gT pitch (shorts)
#define FAP 48      // fA pitch (shorts)
#define PTP 48      // Pt pitch (shorts)
#define PT_HI 5440  // short offset of Pt rows 16..31 inside uA
#define MROWS 144

typedef __attribute__((ext_vector_type(8))) short short8;
typedef __attribute__((ext_vector_type(4))) short short4v;
typedef __attribute__((ext_vector_type(4))) float f32x4;

__device__ __forceinline__ short f2bf(float x) {
    union { __hip_bfloat16 b; short s; } u;
    u.b = __float2bfloat16(x);
    return u.s;
}

// ---- prep: M' bf16 [144][128] = [Wq^T Wk ; (Wk^T bq)^T ; zeros] into d_ws ----
// 72 blocks x 256 threads: 2 rows/block (row uniform per wave-half -> scalar
// broadcast Wq loads). 4 independent accumulators + full unroll -> all 128
// load pairs in one latency window, dependent-fma chain length 32.
__global__ __launch_bounds__(256)
void prep_kernel(const float* __restrict__ Wq, const float* __restrict__ bq,
                 const float* __restrict__ Wk, short* __restrict__ Mp)
{
    const int t = threadIdx.x;
    const int r = blockIdx.x * 2 + (t >> 7);   // 0..143
    const int c = t & 127;
    float a0 = 0.f, a1 = 0.f, a2 = 0.f, a3 = 0.f;
    if (r < CCH) {
        #pragma unroll
        for (int j = 0; j < CCH; j += 4) {
            a0 = fmaf(Wq[(j + 0) * CCH + r], Wk[(j + 0) * CCH + c], a0);
            a1 = fmaf(Wq[(j + 1) * CCH + r], Wk[(j + 1) * CCH + c], a1);
            a2 = fmaf(Wq[(j + 2) * CCH + r], Wk[(j + 2) * CCH + c], a2);
            a3 = fmaf(Wq[(j + 3) * CCH + r], Wk[(j + 3) * CCH + c], a3);
        }
    } else if (r == CCH) {
        #pragma unroll
        for (int o = 0; o < CCH; o += 4) {
            a0 = fmaf(bq[o + 0], Wk[(o + 0) * CCH + c], a0);
            a1 = fmaf(bq[o + 1], Wk[(o + 1) * CCH + c], a1);
            a2 = fmaf(bq[o + 2], Wk[(o + 2) * CCH + c], a2);
            a3 = fmaf(bq[o + 3], Wk[(o + 3) * CCH + c], a3);
        }
    }
    Mp[r * CCH + c] = f2bf((a0 + a1) + (a2 + a3));
}

// St embedded in gT region: St row r lives inside the 16-row gT block (r>>4)
// that only wave (r>>4) reads -> write-after-own-read, no cross-wave race.
#define ST_IDX(r) (((r) >> 4) * 1088 + ((r) & 15) * 36)   // float index into uB

__global__ __launch_bounds__(NTHREADS, 4)
void attn1d_fused(const float* __restrict__ feature,
                  const float* __restrict__ position,
                  const short* __restrict__ Mp,
                  float* __restrict__ out)
{
    // uA: fBt [48][136] (stage->C); Pt overlays fBt rows 0..7 / 40..47 (C-dead)
    // uB: gT [48][136] (B->C); St embedded per-16-row block (C->softmax)
    __shared__ __align__(16) char uA[TWH * PIT * 2];     // 13056
    __shared__ __align__(16) char uB[TWH * PIT * 2];     // 13056
    __shared__ __align__(16) short fA[CCH][FAP];         // 12288  f [c][wl]
    __shared__ float ubias[TWH];                         //   192
                                                         // total 38592 -> 4 blocks/CU
    short (*fBt)[PIT] = (short(*)[PIT])uA;
    short (*gT)[PIT]  = (short(*)[PIT])uB;
    float* Stp        = (float*)uB;
    short* uAs        = (short*)uA;

    const int t    = threadIdx.x;
    const int wid  = t >> 6;
    const int lane = t & 63;
    const int lrow = lane & 15;
    const int lgrp = lane >> 4;

    // XCD-chunked bijective swizzle (2048 % 8 == 0)
    int blk = blockIdx.x;
    blk = (blk & 7) * 256 + (blk >> 3);
    const int wt = blk & 7;
    const int bh = blk >> 3;
    const int h  = bh & (HH - 1);
    const int b  = bh >> 6;
    const int w0 = wt * TW - RR;
    const int base = ((b * CCH) * HH + h) * WW;

    // ---- M-fragments from ws (bf16, direct 16B loads; L2-hot broadcast) ------
    const int mrow = wid * 32;
    short8 Mf[2][4];            // [mf][kk] rows mrow..mrow+31
    #pragma unroll
    for (int mf = 0; mf < 2; ++mf)
        #pragma unroll
        for (int kk = 0; kk < 4; ++kk)
            Mf[mf][kk] = *(const short8*)(Mp + (mrow + mf * 16 + lrow) * CCH
                                             + kk * 32 + lgrp * 8);
    short8 Mf2[4];              // wave 3 only: u-row 128
    if (wid == 3) {
        #pragma unroll
        for (int kk = 0; kk < 4; ++kk)
            Mf2[kk] = *(const short8*)(Mp + (CCH + lrow) * CCH + kk * 32 + lgrp * 8);
    }

    // ---------------- Phase A: stage f as fBt (transposed) + fA --------------
    #pragma unroll
    for (int i = 0; i < 6; ++i) {
        const int idx = i * NTHREADS + t;        // 1536 quads
        const int c  = idx / 12;
        const int wq = idx - c * 12;
        const int w  = w0 + wq * 4;              // quad fully in or out (w0 % 4 == 0)
        float4 fv = {0.f, 0.f, 0.f, 0.f};
        if (w >= 0 && w < WW) {
            const int off = base + c * (HH * WW) + w;
            const float4 fa = *(const float4*)(feature + off);
            const float4 pa = *(const float4*)(position + off);
            fv.x = fa.x + pa.x; fv.y = fa.y + pa.y;
            fv.z = fa.z + pa.z; fv.w = fa.w + pa.w;
        }
        short4v s4;
        s4[0] = f2bf(fv.x); s4[1] = f2bf(fv.y); s4[2] = f2bf(fv.z); s4[3] = f2bf(fv.w);
        *(short4v*)&fA[c][wq * 4] = s4;
        fBt[wq * 4 + 0][c] = s4[0];
        fBt[wq * 4 + 1][c] = s4[1];
        fBt[wq * 4 + 2][c] = s4[2];
        fBt[wq * 4 + 3][c] = s4[3];
    }
    __syncthreads();

    // ---------------- Phase B: g = M f via MFMA (all 4 waves, 32 rows each) ---
    {
        f32x4 acc[2][3];
        #pragma unroll
        for (int mf = 0; mf < 2; ++mf)
            #pragma unroll
            for (int nf = 0; nf < 3; ++nf)
                acc[mf][nf] = (f32x4){0.f, 0.f, 0.f, 0.f};
        f32x4 acc2[3];
        #pragma unroll
        for (int nf = 0; nf < 3; ++nf) acc2[nf] = (f32x4){0.f, 0.f, 0.f, 0.f};

        #pragma unroll
        for (int kk = 0; kk < 4; ++kk) {
            short8 bfr[3];
            #pragma unroll
            for (int nf = 0; nf < 3; ++nf)
                bfr[nf] = *(const short8*)&fBt[nf * 16 + lrow][kk * 32 + lgrp * 8];
            #pragma unroll
            for (int mf = 0; mf < 2; ++mf)
                #pragma unroll
                for (int nf = 0; nf < 3; ++nf)
                    acc[mf][nf] = __builtin_amdgcn_mfma_f32_16x16x32_bf16(
                        Mf[mf][kk], bfr[nf], acc[mf][nf], 0, 0, 0);
            if (wid == 3) {
                #pragma unroll
                for (int nf = 0; nf < 3; ++nf)
                    acc2[nf] = __builtin_amdgcn_mfma_f32_16x16x32_bf16(
                        Mf2[kk], bfr[nf], acc2[nf], 0, 0, 0);
            }
        }

        // writeback g^T (bf16): rows wl = nf*16+lrow, cols mrow+mf*16+lgrp*4+reg
        #pragma unroll
        for (int mf = 0; mf < 2; ++mf)
            #pragma unroll
            for (int nf = 0; nf < 3; ++nf) {
                short4v s;
                #pragma unroll
                for (int reg = 0; reg < 4; ++reg)
                    s[reg] = f2bf(acc[mf][nf][reg]);
                *(short4v*)&gT[nf * 16 + lrow][mrow + mf * 16 + lgrp * 4] = s;
            }
        if (wid == 3 && lgrp == 0) {
            const float isc = 0.08838834764831845f;
            #pragma unroll
            for (int nf = 0; nf < 3; ++nf)
                ubias[nf * 16 + lrow] = acc2[nf][0] * isc;
        }
    }
    __syncthreads();

    // ---------------- Phase C: S^T = (f^T g) / sqrt(C) via MFMA ---------------
    if (wid < 3) {
        const int nf = wid;          // wl' block 0..2
        f32x4 s0 = {0.f,0.f,0.f,0.f}, s1 = {0.f,0.f,0.f,0.f};
        #pragma unroll
        for (int kk = 0; kk < 4; ++kk) {
            const short8 a0 = *(const short8*)&fBt[RR + lrow     ][kk * 32 + lgrp * 8];
            const short8 a1 = *(const short8*)&fBt[RR + 16 + lrow][kk * 32 + lgrp * 8];
            const short8 bb = *(const short8*)&gT[nf * 16 + lrow][kk * 32 + lgrp * 8];
            s0 = __builtin_amdgcn_mfma_f32_16x16x32_bf16(a0, bb, s0, 0, 0, 0);
            s1 = __builtin_amdgcn_mfma_f32_16x16x32_bf16(a1, bb, s1, 0, 0, 0);
        }
        const float isc = 0.08838834764831845f;   // 1/sqrt(128)
        const int sb = ST_IDX(nf * 16 + lrow);    // write inside own gT block
        *(f32x4*)&Stp[sb + lgrp * 4]      = s0 * isc;
        *(f32x4*)&Stp[sb + 16 + lgrp * 4] = s1 * isc;
    } else {
        // wave 3: zero-fill Pt (overlay in fBt rows 0..7 / 40..47, C-dead)
        const short8 z = {0,0,0,0,0,0,0,0};
        #pragma unroll
        for (int i = 0; i < 2; ++i) {
            const int q8 = i * 64 + lane;         // 96 short8 per half
            if (q8 < 96) {
                *(short8*)(uAs + q8 * 8) = z;            // Pt rows 0..15
                *(short8*)(uAs + PT_HI + q8 * 8) = z;    // Pt rows 16..31
            }
        }
    }
    __syncthreads();

    // ---------------- softmax over 17 taps (4 threads/row) -------------------
    if (t < TW * 4) {
        const int w = t >> 2, g = t & 3;
        const int nt = (g == 0) ? 5 : 4;          // taps j = g + 4i, plus j=16 for g==0
        const int prow = (w < 16) ? (w * PTP) : (PT_HI + (w - 16) * PTP);
        float sv[5];
        float mx = -3.0e38f;
        #pragma unroll
        for (int i = 0; i < 5; ++i) {
            if (i < nt) {
                const int j = (i == 4) ? 16 : (g + i * 4);
                const int r = w + j;
                sv[i] = Stp[ST_IDX(r) + w] + ubias[r];
                mx = fmaxf(mx, sv[i]);
            }
        }
        mx = fmaxf(mx, __shfl_xor(mx, 1, 4));
        mx = fmaxf(mx, __shfl_xor(mx, 2, 4));
        float sum = 0.f;
        #pragma unroll
        for (int i = 0; i < 5; ++i)
            if (i < nt) { sv[i] = __expf(sv[i] - mx); sum += sv[i]; }
        sum += __shfl_xor(sum, 1, 4);
        sum += __shfl_xor(sum, 2, 4);
        const float inv = 1.f / sum;
        #pragma unroll
        for (int i = 0; i < 5; ++i)
            if (i < nt) {
                const int j = (i == 4) ? 16 : (g + i * 4);
                uAs[prow + w + j] = f2bf(sv[i] * inv);
            }
    }
    __syncthreads();

    // ---------------- Phase D: out = f . P^T via MFMA -------------------------
    // kk=1 & lgrp>=2 -> k-cols 48..63: both operands substituted zero.
    {
        const int cb = wid * 32;
        const short8 z = {0,0,0,0,0,0,0,0};
        f32x4 d00 = {0.f,0.f,0.f,0.f}, d01 = d00, d10 = d00, d11 = d00;
        #pragma unroll
        for (int kk = 0; kk < 2; ++kk) {
            const int koff = kk * 32 + lgrp * 8;
            const bool live = (koff < TWH);
            short8 a0 = z, a1 = z, b0 = z, b1 = z;
            if (live) {
                a0 = *(const short8*)&fA[cb + lrow     ][koff];
                a1 = *(const short8*)&fA[cb + 16 + lrow][koff];
                b0 = *(const short8*)(uAs + lrow * PTP + koff);           // Pt 0..15
                b1 = *(const short8*)(uAs + PT_HI + lrow * PTP + koff);   // Pt 16..31
            }
            d00 = __builtin_amdgcn_mfma_f32_16x16x32_bf16(a0, b0, d00, 0, 0, 0);
            d01 = __builtin_amdgcn_mfma_f32_16x16x32_bf16(a0, b1, d01, 0, 0, 0);
            d10 = __builtin_amdgcn_mfma_f32_16x16x32_bf16(a1, b0, d10, 0, 0, 0);
            d11 = __builtin_amdgcn_mfma_f32_16x16x32_bf16(a1, b1, d11, 0, 0, 0);
        }
        const int wbase = wt * TW;
        #pragma unroll
        for (int reg = 0; reg < 4; ++reg) {
            const int c0 = cb + lgrp * 4 + reg;
            out[base + c0 * (HH * WW)        + wbase + lrow]      = d00[reg];
            out[base + c0 * (HH * WW)        + wbase + 16 + lrow] = d01[reg];
            out[base + (c0 + 16) * (HH * WW) + wbase + lrow]      = d10[reg];
            out[base + (c0 + 16) * (HH * WW) + wbase + 16 + lrow] = d11[reg];
        }
    }
}

extern "C" void kernel_launch(void* const* d_in, const int* in_sizes, int n_in,
                              void* d_out, int out_size, void* d_ws, size_t ws_size,
                              hipStream_t stream) {
    const float* feature  = (const float*)d_in[0];
    const float* position = (const float*)d_in[1];
    const float* Wq = (const float*)d_in[2];
    const float* bq = (const float*)d_in[3];
    const float* Wk = (const float*)d_in[4];
    const float* bk = (const float*)d_in[5];   // only row-const softmax terms
    (void)bk;
    float* out = (float*)d_out;
    short* Mp  = (short*)d_ws;                 // 144x128 bf16 = 36864 B

    prep_kernel<<<MROWS / 2, 256, 0, stream>>>(Wq, bq, Wk, Mp);
    const dim3 grid(BB * HH * (WW / TW));      // 2048 blocks, 4/CU -> 2 exact rounds
    attn1d_fused<<<grid, NTHREADS, 0, stream>>>(feature, position, Mp, out);
}